// Round 7
// baseline (15.309 us; speedup 1.0000x reference)
//
#include <hip/hip_runtime.h>
#include <hip/hip_bf16.h>

// Block-diagonal attention, x:[8,16,671,64] f32, blocks [0,128),[128,256),
// [256,384),[543,671); gap rows [384,543) -> 0.
// Grid 256 x 512thr (1 WG/CU): each WG pipelines TWO (head,block) problems
// (same head h=wg>>1, blocks (0,1) or (2,3)). Both problems' loads issued
// up-front (reg prefetch); double-buffered LDS; O0 stores deferred past the
// xb1 barrier so they overlap QK1/softmax1. Per-problem math identical to
// the verified round-3 kernel (swapped QK^T, in-lane softmax, in-register
// P via cvt_pk + permlane swaps, PV from LDS V^T).

typedef __attribute__((ext_vector_type(8))) short short8;   // 8 x bf16
typedef __attribute__((ext_vector_type(4))) float floatx4;  // MFMA acc
typedef __attribute__((ext_vector_type(4))) int intx4;
typedef __attribute__((ext_vector_type(2))) unsigned int uint2v;

__device__ __forceinline__ int cvt_pk_bf16(float lo, float hi) {
    int r;
    asm("v_cvt_pk_bf16_f32 %0, %1, %2" : "=v"(r) : "v"(lo), "v"(hi));
    return r;
}

// [X,Y] -> (r0, r1), r0 = [X.g0, X.g2, Y.g0, Y.g2], r1 = [X.g1, X.g3, Y.g1, Y.g3]
// (g = 16-lane group) — exactly the PV B-frag words.
__device__ __forceinline__ uint2v dswap(unsigned a, unsigned b) {
    uint2v t = __builtin_amdgcn_permlane32_swap(a, b, false, false);
    return __builtin_amdgcn_permlane16_swap(t[0], t[1], false, false);
}

#define XB_LD 72    // row stride (ushort): 144B -> conflict-free b128 R/W
#define XT_LD 136   // 272B stride: 16B-aligned b128, conflict-free R/W

// f32->bf16 convert va[4] into xb (row-major), 512 threads cover 128x64
__device__ __forceinline__ void stage_cvt(const float4* va, unsigned short* xb, int tid) {
    #pragma unroll
    for (int it = 0; it < 4; ++it) {
        int i4 = tid + it * 512;
        int r = i4 >> 4, c4 = (i4 & 15) << 2;
        int2 w = make_int2(cvt_pk_bf16(va[it].x, va[it].y),
                           cvt_pk_bf16(va[it].z, va[it].w));
        *reinterpret_cast<int2*>(&xb[r * XB_LD + c4]) = w;
    }
}

// QK^T (swapped) + xt build + softmax. Outputs pk[8][2] (packed bf16 P) and rinv.
__device__ __forceinline__ void qk_softmax(const unsigned short* xb, unsigned short* xt,
                                           int lane, int wid, int (&pk)[8][2], float& rinv) {
    const int l15 = lane & 15;
    const int lhi = lane >> 4;
    const int k0a = lhi * 8;

    short8 bq[2];
    #pragma unroll
    for (int kk = 0; kk < 2; ++kk)
        bq[kk] = *reinterpret_cast<const short8*>(
            &xb[(wid * 16 + l15) * XB_LD + kk * 32 + k0a]);

    floatx4 sT[8];
    #pragma unroll
    for (int mt = 0; mt < 8; ++mt)
        sT[mt] = (floatx4){0.f, 0.f, 0.f, 0.f};

    #pragma unroll
    for (int mt = 0; mt < 8; ++mt) {
        short8 ak[2];
        #pragma unroll
        for (int kk = 0; kk < 2; ++kk)
            ak[kk] = *reinterpret_cast<const short8*>(
                &xb[(mt * 16 + l15) * XB_LD + kk * 32 + k0a]);
        #pragma unroll
        for (int kk = 0; kk < 2; ++kk)
            sT[mt] = __builtin_amdgcn_mfma_f32_16x16x32_bf16(ak[kk], bq[kk], sT[mt], 0, 0, 0);
    }

    // xt = V^T via LDS->LDS transpose (overlaps MFMA above)
    #pragma unroll
    for (int it2 = 0; it2 < 2; ++it2) {
        const int c = wid + it2 * 8;             // t-chunk 0..15 (8 rows each)
        short8 w;
        #pragma unroll
        for (int j = 0; j < 8; ++j)
            w[j] = (short)xb[(c * 8 + j) * XB_LD + lane];
        *reinterpret_cast<short8*>(&xt[lane * XT_LD + c * 8]) = w;
    }

    // softmax: tree max (fuses to v_max3), in-lane exp2, 2 shuffles
    const float C2 = 0.125f * 1.44269504088896340736f;  // scale * log2(e)
    float pm[8];
    #pragma unroll
    for (int mt = 0; mt < 8; ++mt)
        pm[mt] = fmaxf(fmaxf(sT[mt][0], sT[mt][1]), fmaxf(sT[mt][2], sT[mt][3]));
    float m0 = fmaxf(fmaxf(pm[0], pm[1]), fmaxf(pm[2], pm[3]));
    float m1 = fmaxf(fmaxf(pm[4], pm[5]), fmaxf(pm[6], pm[7]));
    float mx = fmaxf(m0, m1);
    mx = fmaxf(mx, __shfl_xor(mx, 16, 64));
    mx = fmaxf(mx, __shfl_xor(mx, 32, 64));
    float sum = 0.f;
    #pragma unroll
    for (int mt = 0; mt < 8; ++mt) {
        float e0 = exp2f((sT[mt][0] - mx) * C2);
        float e1 = exp2f((sT[mt][1] - mx) * C2);
        float e2 = exp2f((sT[mt][2] - mx) * C2);
        float e3 = exp2f((sT[mt][3] - mx) * C2);
        sum += (e0 + e1) + (e2 + e3);
        pk[mt][0] = cvt_pk_bf16(e0, e1);
        pk[mt][1] = cvt_pk_bf16(e2, e3);
    }
    sum += __shfl_xor(sum, 16, 64);
    sum += __shfl_xor(sum, 32, 64);
    rinv = 1.f / sum;
}

// O^T = V^T · P^T, accumulators out (normalization applied at store time)
__device__ __forceinline__ void pv(const unsigned short* xt, const int (&pk)[8][2],
                                   int lane, floatx4 (&oT)[4]) {
    const int l15 = lane & 15;
    const int lhi = lane >> 4;
    const int k0a = lhi * 8;
    #pragma unroll
    for (int ne = 0; ne < 4; ++ne)
        oT[ne] = (floatx4){0.f, 0.f, 0.f, 0.f};
    #pragma unroll
    for (int kk = 0; kk < 4; ++kk) {
        uint2v rA = dswap((unsigned)pk[2 * kk][0], (unsigned)pk[2 * kk + 1][0]);
        uint2v rB = dswap((unsigned)pk[2 * kk][1], (unsigned)pk[2 * kk + 1][1]);
        union { intx4 i; short8 s; } u;
        u.i = (intx4){(int)rA[0], (int)rB[0], (int)rA[1], (int)rB[1]};
        short8 pb = u.s;
        #pragma unroll
        for (int ne = 0; ne < 4; ++ne) {
            short8 av = *reinterpret_cast<const short8*>(
                &xt[(ne * 16 + l15) * XT_LD + kk * 32 + k0a]);
            oT[ne] = __builtin_amdgcn_mfma_f32_16x16x32_bf16(av, pb, oT[ne], 0, 0, 0);
        }
    }
}

__device__ __forceinline__ void store_o(float* op, const floatx4 (&oT)[4], float rinv,
                                        int lane, int wid) {
    const int l15 = lane & 15;
    const int lhi = lane >> 4;
    const int q = wid * 16 + l15;
    #pragma unroll
    for (int ne = 0; ne < 4; ++ne) {
        float4 v = make_float4(oT[ne][0] * rinv, oT[ne][1] * rinv,
                               oT[ne][2] * rinv, oT[ne][3] * rinv);
        *reinterpret_cast<float4*>(&op[q * 64 + ne * 16 + lhi * 4]) = v;
    }
}

__global__ __launch_bounds__(512, 2)
void blockattn_kernel(const float* __restrict__ x, float* __restrict__ out)
{
    __shared__ __align__(16) unsigned short xb0[128 * XB_LD];
    __shared__ __align__(16) unsigned short xt0[64 * XT_LD];
    __shared__ __align__(16) unsigned short xb1[128 * XB_LD];
    __shared__ __align__(16) unsigned short xt1[64 * XT_LD];

    const int wg = blockIdx.x;              // 0..255
    const int h  = wg >> 1;                 // head 0..127
    const int blkA = (wg & 1) * 2;          // 0 or 2
    const int rowA = blkA << 7;             // 0 or 256
    const int rowB = (blkA == 0) ? 128 : 543;  // blkB = 1 or 3
    const float* xpA = x   + ((size_t)h * 671 + rowA) * 64;
    const float* xpB = x   + ((size_t)h * 671 + rowB) * 64;
    float*       opA = out + ((size_t)h * 671 + rowA) * 64;
    float*       opB = out + ((size_t)h * 671 + rowB) * 64;

    const int tid  = threadIdx.x;
    const int lane = tid & 63;
    const int wid  = tid >> 6;              // 0..7

    // ---- issue BOTH problems' loads up front (HBM latency of B hides under A)
    float4 va0[4], va1[4];
    #pragma unroll
    for (int it = 0; it < 4; ++it)
        va0[it] = *reinterpret_cast<const float4*>(xpA + (tid + it * 512) * 4);
    #pragma unroll
    for (int it = 0; it < 4; ++it)
        va1[it] = *reinterpret_cast<const float4*>(xpB + (tid + it * 512) * 4);

    // ---- gap zero for this head (odd WGs own blocks (2,3))
    if (wg & 1) {
        float* gp = out + ((size_t)h * 671 + 384) * 64;
        #pragma unroll
        for (int it = 0; it < 5; ++it) {
            int i4 = tid + it * 512;
            if (i4 < 159 * 16)
                *reinterpret_cast<float4*>(gp + i4 * 4) = make_float4(0.f, 0.f, 0.f, 0.f);
        }
    }

    // ================= problem 0 =================
    stage_cvt(va0, xb0, tid);
    __syncthreads();                        // xb0 ready

    int pk0[8][2]; float rinv0;
    qk_softmax(xb0, xt0, lane, wid, pk0, rinv0);
    __syncthreads();                        // xt0 ready

    floatx4 oT0[4];
    pv(xt0, pk0, lane, oT0);

    // stage problem 1 (va1 arrived long ago; ds_writes to xb1 are independent)
    stage_cvt(va1, xb1, tid);
    __syncthreads();                        // xb1 ready

    // O0 stores issued here: they drain under QK1 + softmax1 compute
    store_o(opA, oT0, rinv0, lane, wid);

    // ================= problem 1 =================
    int pk1[8][2]; float rinv1;
    qk_softmax(xb1, xt1, lane, wid, pk1, rinv1);
    __syncthreads();                        // xt1 ready

    floatx4 oT1[4];
    pv(xt1, pk1, lane, oT1);
    store_o(opB, oT1, rinv1, lane, wid);
}

extern "C" void kernel_launch(void* const* d_in, const int* in_sizes, int n_in,
                              void* d_out, int out_size, void* d_ws, size_t ws_size,
                              hipStream_t stream)
{
    const float* x = (const float*)d_in[0];
    float* out     = (float*)d_out;
    hipLaunchKernelGGL(blockattn_kernel, dim3(256), dim3(512), 0, stream, x, out);
}

// Round 8
// 14.692 us; speedup vs baseline: 1.0420x; 1.0420x over previous
//
#include <hip/hip_runtime.h>
#include <hip/hip_bf16.h>

// Block-diagonal attention, x:[8,16,671,64] f32, blocks [0,128),[128,256),
// [256,384),[543,671); gap rows [384,543) -> 0.
// One WG (512 thr = 8 waves) per (head,block); wave owns 16 q-rows.
// Same structure as round 6, but LDS is UNPADDED + XOR-chunk-swizzled:
//   xb[t][k]: 16B-chunk c stored at c ^ (t&7)   (128 x 64 bf16, 16 KB)
//   xt[e][t]: 16B-chunk c stored at c ^ (e&15)  (64 x 128 bf16, 16 KB)
// This makes every b128 MFMA fragment read/write hit each bank quad-group
// exactly 8 lanes (the b128 minimum) instead of the previous 8-way conflict
// (stride 144B/272B ≡ 4 dwords mod 32 put all fragment lanes on 8 banks).

typedef __attribute__((ext_vector_type(8))) short short8;   // 8 x bf16
typedef __attribute__((ext_vector_type(4))) float floatx4;  // MFMA acc
typedef __attribute__((ext_vector_type(4))) int intx4;
typedef __attribute__((ext_vector_type(2))) unsigned int uint2v;

__device__ __forceinline__ int cvt_pk_bf16(float lo, float hi) {
    int r;
    asm("v_cvt_pk_bf16_f32 %0, %1, %2" : "=v"(r) : "v"(lo), "v"(hi));
    return r;
}

// [X,Y] -> (r0, r1), r0 = [X.g0, X.g2, Y.g0, Y.g2], r1 = [X.g1, X.g3, Y.g1, Y.g3]
// (g = 16-lane group) — exactly the PV B-frag words.
__device__ __forceinline__ uint2v dswap(unsigned a, unsigned b) {
    uint2v t = __builtin_amdgcn_permlane32_swap(a, b, false, false);
    return __builtin_amdgcn_permlane16_swap(t[0], t[1], false, false);
}

__global__ __launch_bounds__(512, 4)
void blockattn_kernel(const float* __restrict__ x, float* __restrict__ out)
{
    __shared__ __align__(16) unsigned short xb[128 * 64]; // swizzled [t][k]
    __shared__ __align__(16) unsigned short xt[64 * 128]; // swizzled [e][t]

    const int wg  = blockIdx.x;
    const int h   = wg >> 2;
    const int blk = wg & 3;
    const int rowbase = (blk < 3) ? (blk << 7) : 543;
    const float* xp = x   + ((size_t)h * 671 + rowbase) * 64;
    float*       op = out + ((size_t)h * 671 + rowbase) * 64;

    const int tid  = threadIdx.x;
    const int lane = tid & 63;
    const int wid  = tid >> 6;          // 0..7

    // ---- stage: each thread owns 2 full 16B chunks (2x2 float4 loads)
    float4 f[2][2];
    #pragma unroll
    for (int it = 0; it < 2; ++it) {
        const int i = tid + it * 512;   // chunk id 0..1023 (8 floats each)
        f[it][0] = *reinterpret_cast<const float4*>(xp + i * 8);
        f[it][1] = *reinterpret_cast<const float4*>(xp + i * 8 + 4);
    }

    // ---- fused gap zero (blk==3 WGs), overlaps load latency
    if (blk == 3) {
        float* gp = out + ((size_t)h * 671 + 384) * 64;
        #pragma unroll
        for (int it = 0; it < 5; ++it) {
            int i4 = tid + it * 512;
            if (i4 < 159 * 16)
                *reinterpret_cast<float4*>(gp + i4 * 4) = make_float4(0.f, 0.f, 0.f, 0.f);
        }
    }

    // ---- convert f32->bf16, one b128 per chunk, swizzled (conflict-free)
    #pragma unroll
    for (int it = 0; it < 2; ++it) {
        const int i = tid + it * 512;
        const int r = i >> 3, c = i & 7;
        union { intx4 i4; short8 s; } u;
        u.i4 = (intx4){cvt_pk_bf16(f[it][0].x, f[it][0].y),
                       cvt_pk_bf16(f[it][0].z, f[it][0].w),
                       cvt_pk_bf16(f[it][1].x, f[it][1].y),
                       cvt_pk_bf16(f[it][1].z, f[it][1].w)};
        *reinterpret_cast<short8*>(&xb[r * 64 + ((c ^ (r & 7)) << 3)]) = u.s;
    }
    __syncthreads();

    const int l15 = lane & 15;
    const int lhi = lane >> 4;

    // ---- S^T = K · Q : this wave's 16 q-rows, C: row=t-part, col=q-part
    short8 bq[2];
    #pragma unroll
    for (int kk = 0; kk < 2; ++kk)
        bq[kk] = *reinterpret_cast<const short8*>(
            &xb[(wid * 16 + l15) * 64 + ((((kk << 2) + lhi) ^ (l15 & 7)) << 3)]);

    floatx4 sT[8];
    #pragma unroll
    for (int mt = 0; mt < 8; ++mt)
        sT[mt] = (floatx4){0.f, 0.f, 0.f, 0.f};

    #pragma unroll
    for (int mt = 0; mt < 8; ++mt) {
        short8 ak[2];
        #pragma unroll
        for (int kk = 0; kk < 2; ++kk)
            ak[kk] = *reinterpret_cast<const short8*>(
                &xb[(mt * 16 + l15) * 64 + ((((kk << 2) + lhi) ^ (l15 & 7)) << 3)]);
        #pragma unroll
        for (int kk = 0; kk < 2; ++kk)
            sT[mt] = __builtin_amdgcn_mfma_f32_16x16x32_bf16(ak[kk], bq[kk], sT[mt], 0, 0, 0);
    }

    // ---- build xt = V^T via LDS->LDS transpose (overlaps MFMA above)
    // read column e=lane of 8 t-rows (2 lanes/dword -> broadcast, free),
    // write one swizzled b128 chunk (8 lanes/quad-group, free)
    #pragma unroll
    for (int it2 = 0; it2 < 2; ++it2) {
        const int c = wid + it2 * 8;             // t-chunk 0..15
        short8 w;
        #pragma unroll
        for (int j = 0; j < 8; ++j)
            w[j] = (short)xb[(c * 8 + j) * 64 + (((lane >> 3) ^ j) << 3) + (lane & 7)];
        *reinterpret_cast<short8*>(&xt[lane * 128 + ((c ^ (lane & 15)) << 3)]) = w;
    }

    // ---- softmax: tree max (v_max3), in-lane exp2, 2 shuffles; pack P bf16
    // Lane (lhi,l15): sT[mt][j] = S[q=wid*16+l15][t=16mt+4*lhi+j]
    const float C2 = 0.125f * 1.44269504088896340736f;  // scale * log2(e)
    int   pk[8][2];
    float rinv;
    {
        float pm[8];
        #pragma unroll
        for (int mt = 0; mt < 8; ++mt)
            pm[mt] = fmaxf(fmaxf(sT[mt][0], sT[mt][1]), fmaxf(sT[mt][2], sT[mt][3]));
        float m0 = fmaxf(fmaxf(pm[0], pm[1]), fmaxf(pm[2], pm[3]));
        float m1 = fmaxf(fmaxf(pm[4], pm[5]), fmaxf(pm[6], pm[7]));
        float mx = fmaxf(m0, m1);
        mx = fmaxf(mx, __shfl_xor(mx, 16, 64));
        mx = fmaxf(mx, __shfl_xor(mx, 32, 64));
        float sum = 0.f;
        #pragma unroll
        for (int mt = 0; mt < 8; ++mt) {
            float e0 = exp2f((sT[mt][0] - mx) * C2);
            float e1 = exp2f((sT[mt][1] - mx) * C2);
            float e2 = exp2f((sT[mt][2] - mx) * C2);
            float e3 = exp2f((sT[mt][3] - mx) * C2);
            sum += (e0 + e1) + (e2 + e3);
            pk[mt][0] = cvt_pk_bf16(e0, e1);
            pk[mt][1] = cvt_pk_bf16(e2, e3);
        }
        sum += __shfl_xor(sum, 16, 64);
        sum += __shfl_xor(sum, 32, 64);
        rinv = 1.f / sum;
    }
    __syncthreads();   // xt complete before PV reads

    // ---- O^T = V^T · P^T : A from swizzled xt, B built via 2 permlane swaps
    floatx4 oT[4];
    #pragma unroll
    for (int ne = 0; ne < 4; ++ne)
        oT[ne] = (floatx4){0.f, 0.f, 0.f, 0.f};

    #pragma unroll
    for (int kk = 0; kk < 4; ++kk) {
        uint2v rA = dswap((unsigned)pk[2 * kk][0], (unsigned)pk[2 * kk + 1][0]);
        uint2v rB = dswap((unsigned)pk[2 * kk][1], (unsigned)pk[2 * kk + 1][1]);
        union { intx4 i; short8 s; } u;
        u.i = (intx4){(int)rA[0], (int)rB[0], (int)rA[1], (int)rB[1]};
        short8 pb = u.s;
        #pragma unroll
        for (int ne = 0; ne < 4; ++ne) {
            short8 av = *reinterpret_cast<const short8*>(
                &xt[(ne * 16 + l15) * 128 + ((((kk << 2) + lhi) ^ l15) << 3)]);
            oT[ne] = __builtin_amdgcn_mfma_f32_16x16x32_bf16(av, pb, oT[ne], 0, 0, 0);
        }
    }

    // ---- epilogue: O[q][e], lane holds 4 consecutive e -> float4 stores
    const int q = wid * 16 + l15;
    #pragma unroll
    for (int ne = 0; ne < 4; ++ne) {
        float4 v = make_float4(oT[ne][0] * rinv, oT[ne][1] * rinv,
                               oT[ne][2] * rinv, oT[ne][3] * rinv);
        *reinterpret_cast<float4*>(&op[q * 64 + ne * 16 + lhi * 4]) = v;
    }
}

extern "C" void kernel_launch(void* const* d_in, const int* in_sizes, int n_in,
                              void* d_out, int out_size, void* d_ws, size_t ws_size,
                              hipStream_t stream)
{
    const float* x = (const float*)d_in[0];
    float* out     = (float*)d_out;
    hipLaunchKernelGGL(blockattn_kernel, dim3(512), dim3(512), 0, stream, x, out);
}

// Round 9
// 14.122 us; speedup vs baseline: 1.0840x; 1.0404x over previous
//
#include <hip/hip_runtime.h>
#include <hip/hip_bf16.h>

// Block-diagonal attention, x:[8,16,671,64] f32, blocks [0,128),[128,256),
// [256,384),[543,671); gap rows [384,543) -> 0.
// One WG (512 thr = 8 waves) per (head,block); wave owns 16 q-rows.
// Round-8 structure (XOR-chunk-swizzled unpadded LDS, swapped QK^T,
// in-lane softmax, in-register P via cvt_pk + permlane swaps), with the
// gap-zero work BALANCED across all 4 WGs of a head (40/40/40/39 rows each)
// instead of concentrated in blk==3 (removes the 2.3x store-tail straggler).

typedef __attribute__((ext_vector_type(8))) short short8;   // 8 x bf16
typedef __attribute__((ext_vector_type(4))) float floatx4;  // MFMA acc
typedef __attribute__((ext_vector_type(4))) int intx4;
typedef __attribute__((ext_vector_type(2))) unsigned int uint2v;

__device__ __forceinline__ int cvt_pk_bf16(float lo, float hi) {
    int r;
    asm("v_cvt_pk_bf16_f32 %0, %1, %2" : "=v"(r) : "v"(lo), "v"(hi));
    return r;
}

// [X,Y] -> (r0, r1), r0 = [X.g0, X.g2, Y.g0, Y.g2], r1 = [X.g1, X.g3, Y.g1, Y.g3]
// (g = 16-lane group) — exactly the PV B-frag words.
__device__ __forceinline__ uint2v dswap(unsigned a, unsigned b) {
    uint2v t = __builtin_amdgcn_permlane32_swap(a, b, false, false);
    return __builtin_amdgcn_permlane16_swap(t[0], t[1], false, false);
}

__global__ __launch_bounds__(512, 4)
void blockattn_kernel(const float* __restrict__ x, float* __restrict__ out)
{
    __shared__ __align__(16) unsigned short xb[128 * 64]; // swizzled [t][k]
    __shared__ __align__(16) unsigned short xt[64 * 128]; // swizzled [e][t]

    const int wg  = blockIdx.x;
    const int h   = wg >> 2;
    const int blk = wg & 3;
    const int rowbase = (blk < 3) ? (blk << 7) : 543;
    const float* xp = x   + ((size_t)h * 671 + rowbase) * 64;
    float*       op = out + ((size_t)h * 671 + rowbase) * 64;

    const int tid  = threadIdx.x;
    const int lane = tid & 63;
    const int wid  = tid >> 6;          // 0..7

    // ---- stage: each thread owns 2 full 16B chunks (2x2 float4 loads)
    float4 f[2][2];
    #pragma unroll
    for (int it = 0; it < 2; ++it) {
        const int i = tid + it * 512;   // chunk id 0..1023 (8 floats each)
        f[it][0] = *reinterpret_cast<const float4*>(xp + i * 8);
        f[it][1] = *reinterpret_cast<const float4*>(xp + i * 8 + 4);
    }

    // ---- gap zero, BALANCED: this WG zeroes rows [384+blk*40, +40) (39 for blk3)
    {
        const int start = 384 + blk * 40;
        const int cnt16 = ((blk < 3) ? 40 : 39) * 16;   // float4 count
        float* gp = out + ((size_t)h * 671 + start) * 64;
        #pragma unroll
        for (int it = 0; it < 2; ++it) {
            int i4 = tid + it * 512;
            if (i4 < cnt16)
                *reinterpret_cast<float4*>(gp + i4 * 4) = make_float4(0.f, 0.f, 0.f, 0.f);
        }
    }

    // ---- convert f32->bf16, one b128 per chunk, swizzled (conflict-free)
    #pragma unroll
    for (int it = 0; it < 2; ++it) {
        const int i = tid + it * 512;
        const int r = i >> 3, c = i & 7;
        union { intx4 i4; short8 s; } u;
        u.i4 = (intx4){cvt_pk_bf16(f[it][0].x, f[it][0].y),
                       cvt_pk_bf16(f[it][0].z, f[it][0].w),
                       cvt_pk_bf16(f[it][1].x, f[it][1].y),
                       cvt_pk_bf16(f[it][1].z, f[it][1].w)};
        *reinterpret_cast<short8*>(&xb[r * 64 + ((c ^ (r & 7)) << 3)]) = u.s;
    }
    __syncthreads();

    const int l15 = lane & 15;
    const int lhi = lane >> 4;

    // ---- S^T = K · Q : this wave's 16 q-rows, C: row=t-part, col=q-part
    short8 bq[2];
    #pragma unroll
    for (int kk = 0; kk < 2; ++kk)
        bq[kk] = *reinterpret_cast<const short8*>(
            &xb[(wid * 16 + l15) * 64 + ((((kk << 2) + lhi) ^ (l15 & 7)) << 3)]);

    floatx4 sT[8];
    #pragma unroll
    for (int mt = 0; mt < 8; ++mt)
        sT[mt] = (floatx4){0.f, 0.f, 0.f, 0.f};

    #pragma unroll
    for (int mt = 0; mt < 8; ++mt) {
        short8 ak[2];
        #pragma unroll
        for (int kk = 0; kk < 2; ++kk)
            ak[kk] = *reinterpret_cast<const short8*>(
                &xb[(mt * 16 + l15) * 64 + ((((kk << 2) + lhi) ^ (l15 & 7)) << 3)]);
        #pragma unroll
        for (int kk = 0; kk < 2; ++kk)
            sT[mt] = __builtin_amdgcn_mfma_f32_16x16x32_bf16(ak[kk], bq[kk], sT[mt], 0, 0, 0);
    }

    // ---- build xt = V^T via LDS->LDS transpose (overlaps MFMA above)
    #pragma unroll
    for (int it2 = 0; it2 < 2; ++it2) {
        const int c = wid + it2 * 8;             // t-chunk 0..15
        short8 w;
        #pragma unroll
        for (int j = 0; j < 8; ++j)
            w[j] = (short)xb[(c * 8 + j) * 64 + (((lane >> 3) ^ j) << 3) + (lane & 7)];
        *reinterpret_cast<short8*>(&xt[lane * 128 + ((c ^ (lane & 15)) << 3)]) = w;
    }

    // ---- softmax: tree max (v_max3), in-lane exp2, 2 shuffles; pack P bf16
    // Lane (lhi,l15): sT[mt][j] = S[q=wid*16+l15][t=16mt+4*lhi+j]
    const float C2 = 0.125f * 1.44269504088896340736f;  // scale * log2(e)
    int   pk[8][2];
    float rinv;
    {
        float pm[8];
        #pragma unroll
        for (int mt = 0; mt < 8; ++mt)
            pm[mt] = fmaxf(fmaxf(sT[mt][0], sT[mt][1]), fmaxf(sT[mt][2], sT[mt][3]));
        float m0 = fmaxf(fmaxf(pm[0], pm[1]), fmaxf(pm[2], pm[3]));
        float m1 = fmaxf(fmaxf(pm[4], pm[5]), fmaxf(pm[6], pm[7]));
        float mx = fmaxf(m0, m1);
        mx = fmaxf(mx, __shfl_xor(mx, 16, 64));
        mx = fmaxf(mx, __shfl_xor(mx, 32, 64));
        float sum = 0.f;
        #pragma unroll
        for (int mt = 0; mt < 8; ++mt) {
            float e0 = exp2f((sT[mt][0] - mx) * C2);
            float e1 = exp2f((sT[mt][1] - mx) * C2);
            float e2 = exp2f((sT[mt][2] - mx) * C2);
            float e3 = exp2f((sT[mt][3] - mx) * C2);
            sum += (e0 + e1) + (e2 + e3);
            pk[mt][0] = cvt_pk_bf16(e0, e1);
            pk[mt][1] = cvt_pk_bf16(e2, e3);
        }
        sum += __shfl_xor(sum, 16, 64);
        sum += __shfl_xor(sum, 32, 64);
        rinv = 1.f / sum;
    }
    __syncthreads();   // xt complete before PV reads

    // ---- O^T = V^T · P^T : A from swizzled xt, B built via 2 permlane swaps
    floatx4 oT[4];
    #pragma unroll
    for (int ne = 0; ne < 4; ++ne)
        oT[ne] = (floatx4){0.f, 0.f, 0.f, 0.f};

    #pragma unroll
    for (int kk = 0; kk < 4; ++kk) {
        uint2v rA = dswap((unsigned)pk[2 * kk][0], (unsigned)pk[2 * kk + 1][0]);
        uint2v rB = dswap((unsigned)pk[2 * kk][1], (unsigned)pk[2 * kk + 1][1]);
        union { intx4 i; short8 s; } u;
        u.i = (intx4){(int)rA[0], (int)rB[0], (int)rA[1], (int)rB[1]};
        short8 pb = u.s;
        #pragma unroll
        for (int ne = 0; ne < 4; ++ne) {
            short8 av = *reinterpret_cast<const short8*>(
                &xt[(ne * 16 + l15) * 128 + ((((kk << 2) + lhi) ^ l15) << 3)]);
            oT[ne] = __builtin_amdgcn_mfma_f32_16x16x32_bf16(av, pb, oT[ne], 0, 0, 0);
        }
    }

    // ---- epilogue: O[q][e], lane holds 4 consecutive e -> float4 stores
    const int q = wid * 16 + l15;
    #pragma unroll
    for (int ne = 0; ne < 4; ++ne) {
        float4 v = make_float4(oT[ne][0] * rinv, oT[ne][1] * rinv,
                               oT[ne][2] * rinv, oT[ne][3] * rinv);
        *reinterpret_cast<float4*>(&op[q * 64 + ne * 16 + lhi * 4]) = v;
    }
}

extern "C" void kernel_launch(void* const* d_in, const int* in_sizes, int n_in,
                              void* d_out, int out_size, void* d_ws, size_t ws_size,
                              hipStream_t stream)
{
    const float* x = (const float*)d_in[0];
    float* out     = (float*)d_out;
    hipLaunchKernelGGL(blockattn_kernel, dim3(512), dim3(512), 0, stream, x, out);
}